// Round 9
// baseline (449.453 us; speedup 1.0000x reference)
//
#include <hip/hip_runtime.h>
#include <hip/hip_bf16.h>
#include <hip/hip_cooperative_groups.h>
namespace cg = cooperative_groups;

constexpr int NN = 256;
constexpr int HH = 128;
constexpr int GG = 512;   // 4H
constexpr int NP = NN * NN;

typedef __attribute__((ext_vector_type(8))) short short8;
typedef __attribute__((ext_vector_type(4))) float f32x4;

// static device scratch
__device__ unsigned short g_xs[(size_t)NP * GG];   // bf16: SE@Wxs+bs, layout [j][i][h*4+g]
__device__ unsigned short g_sebf[(size_t)NP * HH]; // SE as bf16, granule-swizzled per row
__device__ unsigned short g_wfr[20 * 512 * 8];     // B in MFMA-fragment order
__device__ float g_bsp[GG];
__device__ float g_pwh[HH * GG];                   // Wh packed [k][t*4+gate]
__device__ float g_pws[HH * GG];                   // Whs packed [k][t*4+gate]
__device__ float g_kterm[NP];                      // [i][j]
__device__ float g_yeswT[NP];                      // skip_dec transposed [j][i], zero diag
__device__ float g_noskip[NN];
__device__ float g_xg[NN * GG];                    // node_emb@Wx + b, [i][t*4+g]
__device__ float g_xga[NN * GG];                   // xg + h@Wh, [i][t*4+g]
__device__ float g_hws[NN * GG];                   // h@Whs, [i][t*4+g]
__device__ float g_c[NN * HH];
__device__ float g_h[NN * HH];
__device__ float g_sc2[2][NN * HH];                // double-buffered accumulators
__device__ float g_sh2[2][NN * HH];
__device__ float g_nip2[2][NN];
__device__ float g_ip[NN];

__device__ __forceinline__ unsigned short f2bf(float f) {
  unsigned int u = __float_as_uint(f);
  u = (u + 0x7fffu + ((u >> 16) & 1u)) >> 16;
  return (unsigned short)u;
}
__device__ __forceinline__ float bf2f(unsigned short s) {
  return __uint_as_float(((unsigned int)s) << 16);
}
__device__ __forceinline__ float frcp(float x) {
#if __has_builtin(__builtin_amdgcn_rcpf)
  return __builtin_amdgcn_rcpf(x);
#else
  return 1.0f / x;
#endif
}
__device__ __forceinline__ float sigm(float x) { return frcp(1.f + __expf(-x)); }
__device__ __forceinline__ float tanhfast(float x) { return 1.f - 2.f * frcp(__expf(2.f * x) + 1.f); }

// ---------------- fused pre ----------------
// bid: 0-63 init | 64-83 wfr pack | 84-115 Wh/Whs pack | 116-179 xg | 180-435 SE->bf16 swizzled
__global__ __launch_bounds__(512) void k_pre(const float* __restrict__ NE,
                                             const float* __restrict__ Wx,
                                             const float* __restrict__ b,
                                             const float* __restrict__ Wxs,
                                             const float* __restrict__ Wk,
                                             const float* __restrict__ bs,
                                             const float* __restrict__ Wh,
                                             const float* __restrict__ Whs,
                                             const float* __restrict__ SE) {
  const int bid = blockIdx.x;
  const int tid = threadIdx.x;
  if (bid < 64) {
    const int idx = bid * 512 + tid;
    g_c[idx] = 0.f; g_h[idx] = 0.f;
    g_sc2[0][idx] = 0.f; g_sc2[1][idx] = 0.f;
    g_sh2[0][idx] = 0.f; g_sh2[1][idx] = 0.f;
    *(float4*)&g_hws[(size_t)idx * 4] = make_float4(0.f, 0.f, 0.f, 0.f);
    if (idx < NN) {
      g_nip2[0][idx] = 0.f; g_nip2[1][idx] = 0.f;
      g_ip[idx] = (idx == 0) ? 1.f : 0.f;
    }
  } else if (bid < 84) {
    const int bidx = bid - 64;
    const int tile = bidx >> 2, ks = bidx & 3;
    const int ct = tid >> 6, l = tid & 63;
    const int c = ct * 16 + (l & 15);
    const int kbase = ks * 32 + (l >> 4) * 8;
    int src = 0;
    if (tile < 4) src = (c & 3) * 128 + tile * 32 + (c >> 2);
    unsigned short* dst = &g_wfr[((size_t)bidx * 512 + tid) * 8];
#pragma unroll
    for (int e = 0; e < 8; ++e) {
      int k = kbase + e;
      float v = (tile < 4) ? Wxs[k * GG + src] : Wk[k * HH + c];
      dst[e] = f2bf(v);
    }
    if (tile < 4 && ks == 0 && (l >> 4) == 0) g_bsp[tile * 128 + c] = bs[src];
  } else if (bid < 116) {
    const int k = (bid - 84) * 4 + (tid >> 7), t = tid & 127;
    float4 a = make_float4(Wh[k * GG + t], Wh[k * GG + 128 + t], Wh[k * GG + 256 + t], Wh[k * GG + 384 + t]);
    float4 s = make_float4(Whs[k * GG + t], Whs[k * GG + 128 + t], Whs[k * GG + 256 + t], Whs[k * GG + 384 + t]);
    *(float4*)&g_pwh[((size_t)k * HH + t) * 4] = a;
    *(float4*)&g_pws[((size_t)k * HH + t) * 4] = s;
  } else if (bid < 180) {
    __shared__ float ne[4][HH];
    const int sub = tid >> 7, t = tid & 127;
    const int i = (bid - 116) * 4 + sub;
    ne[sub][t] = NE[i * HH + t];
    __syncthreads();
    float a0 = b[t], a1 = b[128 + t], a2 = b[256 + t], a3 = b[384 + t];
    for (int k = 0; k < HH; ++k) {
      float x = ne[sub][k];
      a0 = fmaf(x, Wx[k * GG + t], a0);
      a1 = fmaf(x, Wx[k * GG + 128 + t], a1);
      a2 = fmaf(x, Wx[k * GG + 256 + t], a2);
      a3 = fmaf(x, Wx[k * GG + 384 + t], a3);
    }
    float4 v = make_float4(a0, a1, a2, a3);
    *(float4*)&g_xg[((size_t)i * HH + t) * 4] = v;
    *(float4*)&g_xga[((size_t)i * HH + t) * 4] = v;  // step 0: h=0 -> xga = xg
  } else {
    // SE f32 -> bf16, granule-swizzled: sebf[p][g*8+e] = SE[p][(g^(p&7))*8+e]
    const int p0 = (bid - 180) * 256;
    for (int e = tid; e < 4096; e += 512) {
      const int pl = e >> 4, g = e & 15;
      const int pair = p0 + pl;
      const int gs = g ^ (pair & 7);
      const float* src = SE + (size_t)pair * HH + gs * 8;
      float4 f0 = *(const float4*)(src);
      float4 f1 = *(const float4*)(src + 4);
      short8 v;
      v[0] = (short)f2bf(f0.x); v[1] = (short)f2bf(f0.y); v[2] = (short)f2bf(f0.z); v[3] = (short)f2bf(f0.w);
      v[4] = (short)f2bf(f1.x); v[5] = (short)f2bf(f1.y); v[6] = (short)f2bf(f1.z); v[7] = (short)f2bf(f1.w);
      *(short8*)&g_sebf[(size_t)pair * HH + g * 8] = v;
    }
  }
}

__device__ __forceinline__ void loadB(short8* dst, int tile, int ks, int l) {
  const unsigned short* wf = &g_wfr[((size_t)(tile * 4 + ks)) * 4096 + l * 8];
#pragma unroll
  for (int ct = 0; ct < 8; ++ct) dst[ct] = *(const short8*)(wf + ct * 512);
}

// ---------------- fused GEMM: xs_gates (y=0..3, permuted cols) + kterm (y=4) ----------------
__global__ __launch_bounds__(256) void k_gemm(const float* __restrict__ bk,
                                              const float* __restrict__ Wl) {
  __shared__ __align__(16) char lds[32768];
  const int bid = blockIdx.x;
  const int tile = blockIdx.y;
  const int pb = (bid < 128) ? (bid * 2) : ((bid - 128) * 2 + 1);
  const int pairBase = pb * 128;
  const int tid = threadIdx.x;

  {
    const char* src = (const char*)g_sebf + (size_t)pairBase * 256;
    const int wvoff = (tid >> 6) * 1024;
#pragma unroll
    for (int it = 0; it < 8; ++it) {
      __builtin_amdgcn_global_load_lds(
          (const __attribute__((address_space(1))) unsigned int*)(src + it * 4096 + tid * 16),
          (__attribute__((address_space(3))) unsigned int*)(lds + it * 4096 + wvoff),
          16, 0, 0);
    }
  }
  __syncthreads();

  const int wv = tid >> 6;
  const int l = tid & 63;
  const int l15 = l & 15, lg = l >> 4;

  f32x4 acc[2][8];
#pragma unroll
  for (int rt = 0; rt < 2; ++rt)
#pragma unroll
    for (int ct = 0; ct < 8; ++ct) acc[rt][ct] = (f32x4){0.f, 0.f, 0.f, 0.f};

  short8 bA[8], bB[8];
  loadB(bA, tile, 0, l);
#pragma unroll
  for (int ks = 0; ks < 4; ks += 2) {
    loadB(bB, tile, ks + 1, l);
    {
      const int kb = ks * 64 + lg * 16;
      short8 a[2];
#pragma unroll
      for (int rt = 0; rt < 2; ++rt) {
        int row = wv * 32 + rt * 16 + l15;
        a[rt] = *(const short8*)(lds + row * 256 + (kb ^ ((row & 7) << 4)));
      }
#pragma unroll
      for (int rt = 0; rt < 2; ++rt)
#pragma unroll
        for (int ct = 0; ct < 8; ++ct)
          acc[rt][ct] = __builtin_amdgcn_mfma_f32_16x16x32_bf16(a[rt], bA[ct], acc[rt][ct], 0, 0, 0);
    }
    if (ks + 2 < 4) loadB(bA, tile, ks + 2, l);
    {
      const int kb = (ks + 1) * 64 + lg * 16;
      short8 a[2];
#pragma unroll
      for (int rt = 0; rt < 2; ++rt) {
        int row = wv * 32 + rt * 16 + l15;
        a[rt] = *(const short8*)(lds + row * 256 + (kb ^ ((row & 7) << 4)));
      }
#pragma unroll
      for (int rt = 0; rt < 2; ++rt)
#pragma unroll
        for (int ct = 0; ct < 8; ++ct)
          acc[rt][ct] = __builtin_amdgcn_mfma_f32_16x16x32_bf16(a[rt], bB[ct], acc[rt][ct], 0, 0, 0);
    }
  }

  if (tile < 4) {
#pragma unroll
    for (int rt = 0; rt < 2; ++rt)
#pragma unroll
      for (int ct = 0; ct < 8; ++ct) {
        const int col = ct * 16 + l15;
        const float bsv = g_bsp[tile * 128 + col];
#pragma unroll
        for (int r = 0; r < 4; ++r) {
          int row = wv * 32 + rt * 16 + lg * 4 + r;
          int pair = pairBase + row;
          int jj = pair & 255, ii = pair >> 8;
          if (jj > ii)
            g_xs[((size_t)jj * NN + ii) * GG + tile * 128 + col] = f2bf(acc[rt][ct][r] + bsv);
        }
      }
  } else {
#pragma unroll
    for (int rt = 0; rt < 2; ++rt) {
#pragma unroll
      for (int r = 0; r < 4; ++r) {
        float s = 0.f;
#pragma unroll
        for (int ct = 0; ct < 8; ++ct) {
          int col = ct * 16 + l15;
          float x = acc[rt][ct][r] + bk[col];
          x = fmaxf(x, 0.f);
          s = fmaf(x, Wl[col], s);
        }
#pragma unroll
        for (int m = 1; m < 16; m <<= 1) s += __shfl_xor(s, m, 64);
        int row = wv * 32 + rt * 16 + lg * 4 + r;
        int pair = pairBase + row;
        int jj = pair & 255, ii = pair >> 8;
        if (l15 == 0 && jj >= ii) g_kterm[pair] = s;
      }
    }
  }
}

// ---------------- cooperative mega-kernel: softmax + 4 steps + output ----------------
// grid 256 x 512 (1 block/CU). Phases separated by grid.sync().
__global__ __launch_bounds__(512, 2) void k_coop(const float* __restrict__ Wb,
                                                 const float* __restrict__ bb,
                                                 const int* __restrict__ tix,
                                                 const int* __restrict__ fix,
                                                 const float* __restrict__ Wd,
                                                 const float* __restrict__ bd,
                                                 const int* __restrict__ ei,
                                                 float* __restrict__ out) {
  cg::grid_group grid = cg::this_grid();
  const int bid = blockIdx.x;
  const int tid = threadIdx.x;
  __shared__ float smem[2176];

  // ---- phase 0: masked row softmax -> yeswT, noskip (2 rows per block, bid<128) ----
  if (bid < 128) {
    const int half = tid >> 8, j = tid & 255;
    const int i = bid * 2 + half;
    float* sm = &smem[half * 320];
    float x = (j >= i) ? g_kterm[i * NN + j] : -1e30f;
    sm[j] = x;
    __syncthreads();
    for (int s = 128; s > 0; s >>= 1) { if (j < s) sm[j] = fmaxf(sm[j], sm[j + s]); __syncthreads(); }
    float mx = sm[0];
    __syncthreads();
    float e = (j >= i) ? __expf(x - mx) : 0.f;
    sm[j] = e;
    __syncthreads();
    for (int s = 128; s > 0; s >>= 1) { if (j < s) sm[j] += sm[j + s]; __syncthreads(); }
    float p = e * frcp(sm[0]);
    g_yeswT[j * NN + i] = (j == i) ? 0.f : p;
    if (j == i) g_noskip[i] = p;
  }
  grid.sync();

  for (int s = 0; s < 4; ++s) {
    const int cur = s & 1, nxt = cur ^ 1;
    // ---- phase A: 2048 virtual 128-thread sub-blocks over 2 iterations ----
    // sub 0..255 node, 256..1279 skip(j,ch)
    for (int it = 0; it < 2; ++it) {
      const int sub = bid * 4 + (tid >> 7) + it * 1024;
      const int t = tid & 127;
      if (sub < 256) {
        const int i = sub;
        const float4 a = *(const float4*)&g_xga[((size_t)i * HH + t) * 4];
        float co = g_c[i * HH + t];
        float c2 = sigm(a.y) * co + sigm(a.x) * tanhfast(a.z);
        float h2 = sigm(a.w) * tanhfast(c2);
        float q0 = c2 * Wb[2 * t] + h2 * Wb[2 * (128 + t)];
        float q1 = c2 * Wb[2 * t + 1] + h2 * Wb[2 * (128 + t) + 1];
#pragma unroll
        for (int m = 1; m < 64; m <<= 1) { q0 += __shfl_xor(q0, m, 64); q1 += __shfl_xor(q1, m, 64); }
        if ((t & 63) == 0) { smem[(tid >> 6) * 2] = q0; smem[(tid >> 6) * 2 + 1] = q1; }
        __syncthreads();
        const int k4 = (tid >> 7) * 4;
        float l0 = smem[k4] + smem[k4 + 2] + bb[0];
        float l1 = smem[k4 + 1] + smem[k4 + 3] + bb[1];
        float mm = fmaxf(l0, l1);
        float e0 = __expf(l0 - mm), e1 = __expf(l1 - mm);
        float inv = frcp(e0 + e1);
        float ipv = g_ip[i] * g_noskip[i];
        if (ipv != 0.f) {
          float pbt = ipv * e0 * inv, pbf = ipv * e1 * inv;
          int ti = tix[i], fi = fix[i];
          atomicAdd(&g_sc2[cur][ti * HH + t], c2 * pbt);
          atomicAdd(&g_sh2[cur][ti * HH + t], h2 * pbt);
          atomicAdd(&g_sc2[cur][fi * HH + t], c2 * pbf);
          atomicAdd(&g_sh2[cur][fi * HH + t], h2 * pbf);
          if (t == 0) { atomicAdd(&g_nip2[cur][ti], pbt); atomicAdd(&g_nip2[cur][fi], pbf); }
        }
      } else if (sub < 1280) {
        const int idx = sub - 256;
        const int j = idx >> 2, ch = idx & 3;
        const int i0 = ch * 64;
        float* wsh = &smem[16 + (tid >> 7) * 64];
        const bool act = (i0 < j);
        if (act && t < 64) wsh[t] = g_ip[i0 + t] * g_yeswT[j * NN + i0 + t];
        __syncthreads();
        if (act) {
          const int iN = (j - i0 < 64) ? (j - i0) : 64;
          float accC = 0.f, accH = 0.f, accW = 0.f;
          for (int ii = 0; ii < iN; ++ii) {
            const float wgt = wsh[ii];
            const int i = i0 + ii;
            const ushort4 gv = *(const ushort4*)&g_xs[((size_t)j * NN + i) * GG + t * 4];
            float4 hw = *(const float4*)&g_hws[((size_t)i * HH + t) * 4];
            float xi = bf2f(gv.x) + hw.x;
            float xf = bf2f(gv.y) + hw.y;
            float xg = bf2f(gv.z) + hw.z;
            float xo = bf2f(gv.w) + hw.w;
            float c2 = sigm(xf) * g_c[i * HH + t] + sigm(xi) * tanhfast(xg);
            float h2 = sigm(xo) * tanhfast(c2);
            accC = fmaf(wgt, c2, accC);
            accH = fmaf(wgt, h2, accH);
            accW += wgt;
          }
          if (accW != 0.f) {
            atomicAdd(&g_sc2[cur][j * HH + t], accC);
            atomicAdd(&g_sh2[cur][j * HH + t], accH);
            if (t == 0) atomicAdd(&g_nip2[cur][j], accW);
          }
        }
      }
      __syncthreads();
    }
    grid.sync();

    // ---- phase B: finA (bid<64) | finB (64..95) | zero next accum (96..127) ----
    if (bid < 64) {
      const int j = bid * 4 + (tid >> 7), t = tid & 127;
      float nip = g_nip2[cur][j];
      float d = frcp(nip + 1e-7f);
      g_c[j * HH + t] = g_sc2[cur][j * HH + t] * d;
      g_h[j * HH + t] = g_sh2[cur][j * HH + t] * d;
      if (t == 0) g_ip[j] = nip;
    } else if (bid < 96) {
      if (s < 3) {
        // two vb's per block: vb = (bid-64)*2 + (tid>>8)
        const int vb = (bid - 64) * 2 + (tid >> 8);
        const int tid8 = tid & 255;
        const int m = vb >> 5, i0 = (vb & 31) * 8;
        const float* __restrict__ W = m ? g_pws : g_pwh;
        float* sm = &smem[(tid >> 8) * 1088];
        if (tid8 < 8) sm[1040 + tid8] = frcp(g_nip2[cur][i0 + tid8] + 1e-7f);
        __syncthreads();
        for (int e = tid8; e < 1024; e += 256) {
          const int ii = e >> 7, k = e & 127;
          sm[ii * 129 + k] = g_sh2[cur][(i0 + ii) * HH + k] * sm[1040 + ii];
        }
        __syncthreads();
        for (int hf = 0; hf < 2; ++hf) {
          const int col = hf * 256 + tid8;
          float acc[8];
#pragma unroll
          for (int ii = 0; ii < 8; ++ii) acc[ii] = 0.f;
          for (int k = 0; k < 128; ++k) {
            const float w = W[(size_t)k * GG + col];
#pragma unroll
            for (int ii = 0; ii < 8; ++ii) acc[ii] = fmaf(sm[ii * 129 + k], w, acc[ii]);
          }
          if (m == 0) {
#pragma unroll
            for (int ii = 0; ii < 8; ++ii) {
              const size_t o = (size_t)(i0 + ii) * GG + col;
              g_xga[o] = g_xg[o] + acc[ii];
            }
          } else {
#pragma unroll
            for (int ii = 0; ii < 8; ++ii)
              g_hws[(size_t)(i0 + ii) * GG + col] = acc[ii];
          }
        }
      }
    } else if (bid < 128) {
      if (s < 3) {
        const int gz = (bid - 96) * 512 + tid; // 0..16383
        const float4 z = make_float4(0.f, 0.f, 0.f, 0.f);
        if (gz < 8192) ((float4*)&g_sc2[nxt][0])[gz] = z;
        else ((float4*)&g_sh2[nxt][0])[gz - 8192] = z;
        if (bid == 96 && tid < 256) g_nip2[nxt][tid] = 0.f;
      }
    }
    grid.sync();
  }

  // ---- output: [c[exit], h[exit]] @ Wd + bd ----
  if (bid == 0 && tid < 64) {
    const int v = tid;
    const int e = ei[0];
    float sacc = bd[v];
    for (int h = 0; h < HH; ++h) {
      sacc = fmaf(g_c[e * HH + h], Wd[h * 64 + v], sacc);
      sacc = fmaf(g_h[e * HH + h], Wd[(128 + h) * 64 + v], sacc);
    }
    out[v] = sacc;
  }
}

// ================ fallback path (proven R7 kernels, double-buffer slot 0) ================
__global__ __launch_bounds__(256) void fb_softmax() {
  const int i = blockIdx.x, j = threadIdx.x;
  __shared__ float sm[NN];
  float x = -1e30f;
  if (j >= i) x = g_kterm[i * NN + j];
  sm[j] = x;
  __syncthreads();
  for (int s = 128; s > 0; s >>= 1) { if (j < s) sm[j] = fmaxf(sm[j], sm[j + s]); __syncthreads(); }
  float mx = sm[0];
  __syncthreads();
  float e = (j >= i) ? __expf(x - mx) : 0.f;
  sm[j] = e;
  __syncthreads();
  for (int s = 128; s > 0; s >>= 1) { if (j < s) sm[j] += sm[j + s]; __syncthreads(); }
  float p = e * frcp(sm[0]);
  g_yeswT[j * NN + i] = (j == i) ? 0.f : p;
  if (j == i) g_noskip[i] = p;
}

__global__ __launch_bounds__(128) void fb_step(const float* __restrict__ Wb,
                                               const float* __restrict__ bb,
                                               const int* __restrict__ tix,
                                               const int* __restrict__ fix) {
  const int t = threadIdx.x;
  if (blockIdx.x < 256) {
    const int i = blockIdx.x;
    __shared__ float red[2][2];
    const float4 a = *(const float4*)&g_xga[((size_t)i * HH + t) * 4];
    float co = g_c[i * HH + t];
    float c2 = sigm(a.y) * co + sigm(a.x) * tanhfast(a.z);
    float h2 = sigm(a.w) * tanhfast(c2);
    float q0 = c2 * Wb[2 * t] + h2 * Wb[2 * (128 + t)];
    float q1 = c2 * Wb[2 * t + 1] + h2 * Wb[2 * (128 + t) + 1];
#pragma unroll
    for (int m = 1; m < 64; m <<= 1) { q0 += __shfl_xor(q0, m, 64); q1 += __shfl_xor(q1, m, 64); }
    if ((t & 63) == 0) { red[t >> 6][0] = q0; red[t >> 6][1] = q1; }
    __syncthreads();
    float l0 = red[0][0] + red[1][0] + bb[0];
    float l1 = red[0][1] + red[1][1] + bb[1];
    float mm = fmaxf(l0, l1);
    float e0 = __expf(l0 - mm), e1 = __expf(l1 - mm);
    float inv = frcp(e0 + e1);
    float ipv = g_ip[i] * g_noskip[i];
    if (ipv != 0.f) {
      float pbt = ipv * e0 * inv, pbf = ipv * e1 * inv;
      int ti = tix[i], fi = fix[i];
      atomicAdd(&g_sc2[0][ti * HH + t], c2 * pbt);
      atomicAdd(&g_sh2[0][ti * HH + t], h2 * pbt);
      atomicAdd(&g_sc2[0][fi * HH + t], c2 * pbf);
      atomicAdd(&g_sh2[0][fi * HH + t], h2 * pbf);
      if (t == 0) { atomicAdd(&g_nip2[0][ti], pbt); atomicAdd(&g_nip2[0][fi], pbf); }
    }
  } else {
    const int idx = blockIdx.x - 256;
    const int j = idx >> 2, ch = idx & 3;
    const int i0 = ch * 64;
    if (i0 >= j) return;
    const int iN = (j - i0 < 64) ? (j - i0) : 64;
    __shared__ float wsh[64];
    if (t < 64) wsh[t] = g_ip[i0 + t] * g_yeswT[j * NN + i0 + t];
    __syncthreads();
    float accC = 0.f, accH = 0.f, accW = 0.f;
    for (int ii = 0; ii < iN; ++ii) {
      const float wgt = wsh[ii];
      const int i = i0 + ii;
      const ushort4 gv = *(const ushort4*)&g_xs[((size_t)j * NN + i) * GG + t * 4];
      float4 hw = *(const float4*)&g_hws[((size_t)i * HH + t) * 4];
      float xi = bf2f(gv.x) + hw.x;
      float xf = bf2f(gv.y) + hw.y;
      float xg = bf2f(gv.z) + hw.z;
      float xo = bf2f(gv.w) + hw.w;
      float c2 = sigm(xf) * g_c[i * HH + t] + sigm(xi) * tanhfast(xg);
      float h2 = sigm(xo) * tanhfast(c2);
      accC = fmaf(wgt, c2, accC);
      accH = fmaf(wgt, h2, accH);
      accW += wgt;
    }
    if (accW != 0.f) {
      atomicAdd(&g_sc2[0][j * HH + t], accC);
      atomicAdd(&g_sh2[0][j * HH + t], accH);
      if (t == 0) atomicAdd(&g_nip2[0][j], accW);
    }
  }
}

__global__ __launch_bounds__(512) void fb_finA() {
  const int tid = threadIdx.x;
  const int j = blockIdx.x * 4 + (tid >> 7), t = tid & 127;
  float nip = g_nip2[0][j];
  float d = frcp(nip + 1e-7f);
  g_c[j * HH + t] = g_sc2[0][j * HH + t] * d;
  g_h[j * HH + t] = g_sh2[0][j * HH + t] * d;
  g_sc2[0][j * HH + t] = 0.f;
  g_sh2[0][j * HH + t] = 0.f;
  if (t == 0) { g_ip[j] = nip; g_nip2[0][j] = 0.f; }
}

__global__ __launch_bounds__(256) void fb_finB() {
  __shared__ float hsm[64 * 132];
  __shared__ float wsmT[4 * 128];
  const int b = blockIdx.x;
  const int cg_ = b >> 1, m = b & 1;
  const int tid = threadIdx.x;
  const float* __restrict__ W = m ? g_pws : g_pwh;
  for (int e = tid; e < 512; e += 256) {
    const int cc = e >> 7, k = e & 127;
    wsmT[cc * 128 + k] = W[(size_t)k * 512 + cg_ * 4 + cc];
  }
  const int il = tid >> 2, cc = tid & 3;
  for (int it = 0; it < 4; ++it) {
    const int i0 = it * 64;
    __syncthreads();
    for (int e = tid; e < 2048; e += 256) {
      const int r = e >> 5, kq = e & 31;
      *(float4*)&hsm[r * 132 + kq * 4] = *(const float4*)&g_h[(size_t)(i0 + r) * HH + kq * 4];
    }
    __syncthreads();
    float acc = 0.f;
#pragma unroll 8
    for (int k4 = 0; k4 < 32; ++k4) {
      const float4 h4 = *(const float4*)&hsm[il * 132 + k4 * 4];
      const float4 w4 = *(const float4*)&wsmT[cc * 128 + k4 * 4];
      acc = fmaf(h4.x, w4.x, acc); acc = fmaf(h4.y, w4.y, acc);
      acc = fmaf(h4.z, w4.z, acc); acc = fmaf(h4.w, w4.w, acc);
    }
    const size_t o = (size_t)(i0 + il) * 512 + cg_ * 4 + cc;
    if (m == 0) g_xga[o] = g_xg[o] + acc;
    else g_hws[o] = acc;
  }
}

__global__ __launch_bounds__(64) void k_out(const float* __restrict__ Wd,
                                            const float* __restrict__ bd,
                                            const int* __restrict__ ei,
                                            float* __restrict__ out) {
  const int v = threadIdx.x;
  const int e = ei[0];
  float s = bd[v];
  for (int h = 0; h < HH; ++h) {
    s = fmaf(g_c[e * HH + h], Wd[h * 64 + v], s);
    s = fmaf(g_h[e * HH + h], Wd[(128 + h) * 64 + v], s);
  }
  out[v] = s;
}

extern "C" void kernel_launch(void* const* d_in, const int* in_sizes, int n_in,
                              void* d_out, int out_size, void* d_ws, size_t ws_size,
                              hipStream_t stream) {
  const float* NE  = (const float*)d_in[0];
  const float* SE  = (const float*)d_in[1];
  const float* Wx  = (const float*)d_in[2];
  const float* Wh  = (const float*)d_in[3];
  const float* b   = (const float*)d_in[4];
  const float* Wxs = (const float*)d_in[5];
  const float* Whs = (const float*)d_in[6];
  const float* bs  = (const float*)d_in[7];
  const float* Wb  = (const float*)d_in[8];
  const float* bb  = (const float*)d_in[9];
  const float* Wk  = (const float*)d_in[10];
  const float* bk  = (const float*)d_in[11];
  // d_in[12] Wq, d_in[13] bq, d_in[15] bl: cancel in row-softmax -> unused
  const float* Wl  = (const float*)d_in[14];
  const float* Wd  = (const float*)d_in[16];
  const float* bd  = (const float*)d_in[17];
  // d_in[18] skip_mask is structurally triu -> computed as (j >= i)
  const int* tix = (const int*)d_in[19];
  const int* fix = (const int*)d_in[20];
  const int* ei  = (const int*)d_in[21];
  float* out = (float*)d_out;

  k_pre<<<436, 512, 0, stream>>>(NE, Wx, b, Wxs, Wk, bs, Wh, Whs, SE);
  k_gemm<<<dim3(384, 5), 256, 0, stream>>>(bk, Wl);

  void* cargs[] = {(void*)&Wb, (void*)&bb, (void*)&tix, (void*)&fix,
                   (void*)&Wd, (void*)&bd, (void*)&ei, (void*)&out};
  hipError_t cerr = hipLaunchCooperativeKernel((const void*)k_coop, dim3(256), dim3(512),
                                               cargs, 0, stream);
  if (cerr != hipSuccess) {
    // fallback: proven multi-kernel path
    fb_softmax<<<256, 256, 0, stream>>>();
    for (int s = 0; s < 4; ++s) {
      fb_step<<<256 + 1024, 128, 0, stream>>>(Wb, bb, tix, fix);
      fb_finA<<<64, 512, 0, stream>>>();
      if (s != 3) fb_finB<<<256, 256, 0, stream>>>();
    }
    k_out<<<1, 64, 0, stream>>>(Wd, bd, ei, out);
  }
}

// Round 10
// 159.608 us; speedup vs baseline: 2.8160x; 2.8160x over previous
//
#include <hip/hip_runtime.h>
#include <hip/hip_bf16.h>

constexpr int NN = 256;
constexpr int HH = 128;
constexpr int GG = 512;   // 4H
constexpr int NP = NN * NN;

typedef __attribute__((ext_vector_type(8))) short short8;
typedef __attribute__((ext_vector_type(4))) float f32x4;

// static device scratch
__device__ unsigned short g_xs[(size_t)NP * GG]; // bf16: SE@Wxs+bs, layout [j][i][h*4+g]
__device__ unsigned short g_wfr[20 * 512 * 8];   // B in MFMA-fragment order
__device__ float g_bsp[GG];                      // bs permuted to col' order
__device__ float g_pwh[HH * GG];                 // Wh packed [k][t*4+gate]
__device__ float g_pws[HH * GG];                 // Whs packed [k][t*4+gate]
__device__ float g_kterm[NP];                    // [i][j]
__device__ float g_yeswT[NP];                    // skip_dec transposed [j][i], zero diag
__device__ float g_noskip[NN];
__device__ float g_xg[NN * GG];                  // node_emb@Wx + b, [i][t*4+g]
__device__ float g_xga[NN * GG];                 // xg + h@Wh, [i][t*4+g]
__device__ float g_hws[NN * GG];                 // h@Whs, [i][t*4+g]
__device__ float g_c[NN * HH];
__device__ float g_h[NN * HH];
__device__ float g_sc[NN * HH];
__device__ float g_sh[NN * HH];
__device__ float g_ip[NN];
__device__ float g_nip[NN];

__device__ __forceinline__ unsigned short f2bf(float f) {
  unsigned int u = __float_as_uint(f);
  u = (u + 0x7fffu + ((u >> 16) & 1u)) >> 16;
  return (unsigned short)u;
}
__device__ __forceinline__ float bf2f(unsigned short s) {
  return __uint_as_float(((unsigned int)s) << 16);
}
__device__ __forceinline__ float frcp(float x) {
#if __has_builtin(__builtin_amdgcn_rcpf)
  return __builtin_amdgcn_rcpf(x);
#else
  return 1.0f / x;
#endif
}
__device__ __forceinline__ float sigm(float x) { return frcp(1.f + __expf(-x)); }
__device__ __forceinline__ float tanhfast(float x) { return 1.f - 2.f * frcp(__expf(2.f * x) + 1.f); }

// ---------------- fused pre ----------------
// bid: 0-63 init | 64-83 wfr pack | 84-115 Wh/Whs pack | 116-179 xg
__global__ __launch_bounds__(512) void k_pre(const float* __restrict__ NE,
                                             const float* __restrict__ Wx,
                                             const float* __restrict__ b,
                                             const float* __restrict__ Wxs,
                                             const float* __restrict__ Wk,
                                             const float* __restrict__ bs,
                                             const float* __restrict__ Wh,
                                             const float* __restrict__ Whs) {
  const int bid = blockIdx.x;
  const int tid = threadIdx.x;
  if (bid < 64) {
    const int idx = bid * 512 + tid;
    g_sc[idx] = 0.f; g_sh[idx] = 0.f; g_c[idx] = 0.f; g_h[idx] = 0.f;
    *(float4*)&g_hws[(size_t)idx * 4] = make_float4(0.f, 0.f, 0.f, 0.f);
    if (idx < NN) { g_nip[idx] = 0.f; g_ip[idx] = (idx == 0) ? 1.f : 0.f; }
  } else if (bid < 84) {
    const int bidx = bid - 64;
    const int tile = bidx >> 2, ks = bidx & 3;
    const int ct = tid >> 6, l = tid & 63;
    const int c = ct * 16 + (l & 15);
    const int kbase = ks * 32 + (l >> 4) * 8;
    int src = 0;
    if (tile < 4) src = (c & 3) * 128 + tile * 32 + (c >> 2);
    unsigned short* dst = &g_wfr[((size_t)bidx * 512 + tid) * 8];
#pragma unroll
    for (int e = 0; e < 8; ++e) {
      int k = kbase + e;
      float v = (tile < 4) ? Wxs[k * GG + src] : Wk[k * HH + c];
      dst[e] = f2bf(v);
    }
    if (tile < 4 && ks == 0 && (l >> 4) == 0) g_bsp[tile * 128 + c] = bs[src];
  } else if (bid < 116) {
    const int k = (bid - 84) * 4 + (tid >> 7), t = tid & 127;
    float4 a = make_float4(Wh[k * GG + t], Wh[k * GG + 128 + t], Wh[k * GG + 256 + t], Wh[k * GG + 384 + t]);
    float4 s = make_float4(Whs[k * GG + t], Whs[k * GG + 128 + t], Whs[k * GG + 256 + t], Whs[k * GG + 384 + t]);
    *(float4*)&g_pwh[((size_t)k * HH + t) * 4] = a;
    *(float4*)&g_pws[((size_t)k * HH + t) * 4] = s;
  } else {
    __shared__ float ne[4][HH];
    const int sub = tid >> 7, t = tid & 127;
    const int i = (bid - 116) * 4 + sub;
    ne[sub][t] = NE[i * HH + t];
    __syncthreads();
    float a0 = b[t], a1 = b[128 + t], a2 = b[256 + t], a3 = b[384 + t];
    for (int k = 0; k < HH; ++k) {
      float x = ne[sub][k];
      a0 = fmaf(x, Wx[k * GG + t], a0);
      a1 = fmaf(x, Wx[k * GG + 128 + t], a1);
      a2 = fmaf(x, Wx[k * GG + 256 + t], a2);
      a3 = fmaf(x, Wx[k * GG + 384 + t], a3);
    }
    float4 v = make_float4(a0, a1, a2, a3);
    *(float4*)&g_xg[((size_t)i * HH + t) * 4] = v;
    *(float4*)&g_xga[((size_t)i * HH + t) * 4] = v;  // step 0: h=0 -> xga = xg
  }
}

__device__ __forceinline__ void loadB(short8* dst, int tile, int ks, int l) {
  const unsigned short* wf = &g_wfr[((size_t)(tile * 4 + ks)) * 4096 + l * 8];
#pragma unroll
  for (int ct = 0; ct < 8; ++ct) dst[ct] = *(const short8*)(wf + ct * 512);
}

// ---------------- fused GEMM: xs_gates (tiles 0..3, permuted cols) + kterm (tile 4) ----------------
// 1D grid 1920, XCD-grouped: the 5 col-tiles of one A-tile land on the same XCD.
__global__ __launch_bounds__(256) void k_gemm(const float* __restrict__ SE,
                                              const float* __restrict__ bk,
                                              const float* __restrict__ Wl) {
  __shared__ __align__(16) char lds[32768];
  const int bid = blockIdx.x;
  const int xcd = bid & 7;
  const int w = bid >> 3;           // 0..239
  const int x = (w / 5) * 8 + xcd;  // 0..383 (A-tile index)
  const int tile = w % 5;
  const int pb = (x < 128) ? (x * 2) : ((x - 128) * 2 + 1);
  const int pairBase = pb * 128;
  const int tid = threadIdx.x;

  // A: [row][k] f32->bf16, swizzled (byte ^= (row&7)<<4)
  for (int cc = tid; cc < 2048; cc += 256) {
    int row = cc >> 4, kc = cc & 15;
    const float* src = SE + (size_t)(pairBase + row) * HH + kc * 8;
    float4 f0 = *(const float4*)(src);
    float4 f1 = *(const float4*)(src + 4);
    short8 v;
    v[0] = (short)f2bf(f0.x); v[1] = (short)f2bf(f0.y); v[2] = (short)f2bf(f0.z); v[3] = (short)f2bf(f0.w);
    v[4] = (short)f2bf(f1.x); v[5] = (short)f2bf(f1.y); v[6] = (short)f2bf(f1.z); v[7] = (short)f2bf(f1.w);
    *(short8*)(lds + row * 256 + ((kc * 16) ^ ((row & 7) << 4))) = v;
  }
  __syncthreads();

  const int wv = tid >> 6;
  const int l = tid & 63;
  const int l15 = l & 15, lg = l >> 4;

  f32x4 acc[2][8];
#pragma unroll
  for (int rt = 0; rt < 2; ++rt)
#pragma unroll
    for (int ct = 0; ct < 8; ++ct) acc[rt][ct] = (f32x4){0.f, 0.f, 0.f, 0.f};

  short8 bA[8], bB[8];
  loadB(bA, tile, 0, l);
#pragma unroll
  for (int ks = 0; ks < 4; ks += 2) {
    loadB(bB, tile, ks + 1, l);
    {
      const int kb = ks * 64 + lg * 16;
      short8 a[2];
#pragma unroll
      for (int rt = 0; rt < 2; ++rt) {
        int row = wv * 32 + rt * 16 + l15;
        a[rt] = *(const short8*)(lds + row * 256 + (kb ^ ((row & 7) << 4)));
      }
#pragma unroll
      for (int rt = 0; rt < 2; ++rt)
#pragma unroll
        for (int ct = 0; ct < 8; ++ct)
          acc[rt][ct] = __builtin_amdgcn_mfma_f32_16x16x32_bf16(a[rt], bA[ct], acc[rt][ct], 0, 0, 0);
    }
    if (ks + 2 < 4) loadB(bA, tile, ks + 2, l);
    {
      const int kb = (ks + 1) * 64 + lg * 16;
      short8 a[2];
#pragma unroll
      for (int rt = 0; rt < 2; ++rt) {
        int row = wv * 32 + rt * 16 + l15;
        a[rt] = *(const short8*)(lds + row * 256 + (kb ^ ((row & 7) << 4)));
      }
#pragma unroll
      for (int rt = 0; rt < 2; ++rt)
#pragma unroll
        for (int ct = 0; ct < 8; ++ct)
          acc[rt][ct] = __builtin_amdgcn_mfma_f32_16x16x32_bf16(a[rt], bB[ct], acc[rt][ct], 0, 0, 0);
    }
  }

  if (tile < 4) {
    // stores into transposed layout g_xs[j][i][h*4+g]
#pragma unroll
    for (int rt = 0; rt < 2; ++rt)
#pragma unroll
      for (int ct = 0; ct < 8; ++ct) {
        const int col = ct * 16 + l15;
        const float bsv = g_bsp[tile * 128 + col];
#pragma unroll
        for (int r = 0; r < 4; ++r) {
          int row = wv * 32 + rt * 16 + lg * 4 + r;
          int pair = pairBase + row;
          int jj = pair & 255, ii = pair >> 8;
          if (jj > ii)
            g_xs[((size_t)jj * NN + ii) * GG + tile * 128 + col] = f2bf(acc[rt][ct][r] + bsv);
        }
      }
  } else {
    // kterm: sum_h relu(x + bk) * Wl[h]
#pragma unroll
    for (int rt = 0; rt < 2; ++rt) {
#pragma unroll
      for (int r = 0; r < 4; ++r) {
        float s = 0.f;
#pragma unroll
        for (int ct = 0; ct < 8; ++ct) {
          int col = ct * 16 + l15;
          float x2 = acc[rt][ct][r] + bk[col];
          x2 = fmaxf(x2, 0.f);
          s = fmaf(x2, Wl[col], s);
        }
#pragma unroll
        for (int m = 1; m < 16; m <<= 1) s += __shfl_xor(s, m, 64);
        int row = wv * 32 + rt * 16 + lg * 4 + r;
        int pair = pairBase + row;
        int jj = pair & 255, ii = pair >> 8;
        if (l15 == 0 && jj >= ii) g_kterm[pair] = s;
      }
    }
  }
}

// ---------------- masked row softmax -> yeswT (transposed), no_skip ----------------
__global__ __launch_bounds__(256) void k_softmax() {
  const int i = blockIdx.x, j = threadIdx.x;
  __shared__ float sm[NN];
  float x = -1e30f;
  if (j >= i) x = g_kterm[i * NN + j];
  sm[j] = x;
  __syncthreads();
  for (int s = 128; s > 0; s >>= 1) { if (j < s) sm[j] = fmaxf(sm[j], sm[j + s]); __syncthreads(); }
  float mx = sm[0];
  __syncthreads();
  float e = (j >= i) ? __expf(x - mx) : 0.f;
  sm[j] = e;
  __syncthreads();
  for (int s = 128; s > 0; s >>= 1) { if (j < s) sm[j] += sm[j + s]; __syncthreads(); }
  float p = e * frcp(sm[0]);
  g_yeswT[j * NN + i] = (j == i) ? 0.f : p;
  if (j == i) g_noskip[i] = p;
}

// ---------------- per-step fused: node (blocks 0-255) + skip chunk16 (256+) ----------------
__global__ __launch_bounds__(128) void k_step(const float* __restrict__ Wb,
                                              const float* __restrict__ bb,
                                              const int* __restrict__ tix,
                                              const int* __restrict__ fix) {
  const int t = threadIdx.x;
  if (blockIdx.x < 256) {
    const int i = blockIdx.x;
    const float ipi = g_ip[i];
    if (ipi == 0.f) return;                      // dynamic sparsity (step 0: 255/256 exit)
    __shared__ float red[2][2];
    const float4 a = *(const float4*)&g_xga[((size_t)i * HH + t) * 4];
    float co = g_c[i * HH + t];
    float c2 = sigm(a.y) * co + sigm(a.x) * tanhfast(a.z);
    float h2 = sigm(a.w) * tanhfast(c2);
    float q0 = c2 * Wb[2 * t] + h2 * Wb[2 * (128 + t)];
    float q1 = c2 * Wb[2 * t + 1] + h2 * Wb[2 * (128 + t) + 1];
#pragma unroll
    for (int m = 1; m < 64; m <<= 1) { q0 += __shfl_xor(q0, m, 64); q1 += __shfl_xor(q1, m, 64); }
    if ((t & 63) == 0) { red[t >> 6][0] = q0; red[t >> 6][1] = q1; }
    __syncthreads();
    float l0 = red[0][0] + red[1][0] + bb[0];
    float l1 = red[0][1] + red[1][1] + bb[1];
    float mm = fmaxf(l0, l1);
    float e0 = __expf(l0 - mm), e1 = __expf(l1 - mm);
    float inv = frcp(e0 + e1);
    float ipv = ipi * g_noskip[i];
    if (ipv != 0.f) {
      float pbt = ipv * e0 * inv, pbf = ipv * e1 * inv;
      int ti = tix[i], fi = fix[i];
      atomicAdd(&g_sc[ti * HH + t], c2 * pbt);
      atomicAdd(&g_sh[ti * HH + t], h2 * pbt);
      atomicAdd(&g_sc[fi * HH + t], c2 * pbf);
      atomicAdd(&g_sh[fi * HH + t], h2 * pbf);
      if (t == 0) { atomicAdd(&g_nip[ti], pbt); atomicAdd(&g_nip[fi], pbf); }
    }
  } else {
    const int idx = blockIdx.x - 256;
    const int j = idx >> 4, ch = idx & 15;
    const int i0 = ch * 16;
    if (i0 >= j) return;
    const int iN = (j - i0 < 16) ? (j - i0) : 16;
    __shared__ float wsh[16];
    if (t < 16) wsh[t] = (t < iN) ? g_ip[i0 + t] * g_yeswT[j * NN + i0 + t] : 0.f;
    __syncthreads();
    float s16 = 0.f;
#pragma unroll
    for (int q = 0; q < 16; ++q) s16 += wsh[q];
    if (s16 == 0.f) return;                      // chunk fully inactive (step 0: 15/16 exit)
    float accC = 0.f, accH = 0.f, accW = 0.f;
    for (int ii = 0; ii < iN; ++ii) {
      const float wgt = wsh[ii];
      const int i = i0 + ii;
      const ushort4 gv = *(const ushort4*)&g_xs[((size_t)j * NN + i) * GG + t * 4];
      float4 hw = *(const float4*)&g_hws[((size_t)i * HH + t) * 4];
      float xi = bf2f(gv.x) + hw.x;
      float xf = bf2f(gv.y) + hw.y;
      float xg = bf2f(gv.z) + hw.z;
      float xo = bf2f(gv.w) + hw.w;
      float c2 = sigm(xf) * g_c[i * HH + t] + sigm(xi) * tanhfast(xg);
      float h2 = sigm(xo) * tanhfast(c2);
      accC = fmaf(wgt, c2, accC);
      accH = fmaf(wgt, h2, accH);
      accW += wgt;
    }
    atomicAdd(&g_sc[j * HH + t], accC);
    atomicAdd(&g_sh[j * HH + t], accH);
    if (t == 0) atomicAdd(&g_nip[j], accW);
  }
}

// ---------------- per-step finish: normalize + GEMVs for next step (+ output on last) ----------------
// 64 blocks x 256 threads, 4 j's per block.
__global__ __launch_bounds__(256) void k_finish(const int last,
                                                const float* __restrict__ Wd,
                                                const float* __restrict__ bd,
                                                const int* __restrict__ ei,
                                                float* __restrict__ out) {
  const int j0 = blockIdx.x * 4;
  const int tid = threadIdx.x;
  __shared__ float hsm[4][HH];
  __shared__ float nipsh[4];
  if (tid < 4) {
    const int j = j0 + tid;
    float nip = g_nip[j];
    nipsh[tid] = nip;
    g_ip[j] = nip;
    g_nip[j] = 0.f;
  }
  __syncthreads();
#pragma unroll
  for (int s = 0; s < 2; ++s) {
    const int slot = tid + s * 256;
    const int jj = slot >> 7, t = slot & 127;
    const int j = j0 + jj;
    float d = frcp(nipsh[jj] + 1e-7f);
    float cv = g_sc[j * HH + t] * d;
    float hv = g_sh[j * HH + t] * d;
    g_c[j * HH + t] = cv;
    g_h[j * HH + t] = hv;
    hsm[jj][t] = hv;
    g_sc[j * HH + t] = 0.f;
    g_sh[j * HH + t] = 0.f;
  }
  __syncthreads();
  if (last) {
    const int e = ei[0];
    if (e >= j0 && e < j0 + 4 && tid < 64) {
      const int v = tid;
      float sacc = bd[v];
      const float* cc = &g_c[e * HH];
      const float* hh = &g_h[e * HH];
      for (int h = 0; h < HH; ++h) {
        sacc = fmaf(cc[h], Wd[h * 64 + v], sacc);
        sacc = fmaf(hh[h], Wd[(128 + h) * 64 + v], sacc);
      }
      out[v] = sacc;
    }
    return;
  }
  // GEMV: m = tid>>7 selects {Wh->xga, Whs->hws}; col t = tid&127; all 4 j's, full K.
  const int m = tid >> 7, t = tid & 127;
  const float* __restrict__ W = m ? g_pws : g_pwh;
  float4 a0 = make_float4(0.f, 0.f, 0.f, 0.f), a1 = a0, a2 = a0, a3 = a0;
#pragma unroll 4
  for (int k = 0; k < HH; ++k) {
    const float4 w = *(const float4*)&W[((size_t)k * HH + t) * 4];
    const float h0 = hsm[0][k], h1 = hsm[1][k], h2 = hsm[2][k], h3 = hsm[3][k];
    a0.x = fmaf(h0, w.x, a0.x); a0.y = fmaf(h0, w.y, a0.y); a0.z = fmaf(h0, w.z, a0.z); a0.w = fmaf(h0, w.w, a0.w);
    a1.x = fmaf(h1, w.x, a1.x); a1.y = fmaf(h1, w.y, a1.y); a1.z = fmaf(h1, w.z, a1.z); a1.w = fmaf(h1, w.w, a1.w);
    a2.x = fmaf(h2, w.x, a2.x); a2.y = fmaf(h2, w.y, a2.y); a2.z = fmaf(h2, w.z, a2.z); a2.w = fmaf(h2, w.w, a2.w);
    a3.x = fmaf(h3, w.x, a3.x); a3.y = fmaf(h3, w.y, a3.y); a3.z = fmaf(h3, w.z, a3.z); a3.w = fmaf(h3, w.w, a3.w);
  }
  if (m == 0) {
    float4 x0 = *(const float4*)&g_xg[((size_t)(j0 + 0) * HH + t) * 4];
    float4 x1 = *(const float4*)&g_xg[((size_t)(j0 + 1) * HH + t) * 4];
    float4 x2 = *(const float4*)&g_xg[((size_t)(j0 + 2) * HH + t) * 4];
    float4 x3 = *(const float4*)&g_xg[((size_t)(j0 + 3) * HH + t) * 4];
    *(float4*)&g_xga[((size_t)(j0 + 0) * HH + t) * 4] = make_float4(x0.x + a0.x, x0.y + a0.y, x0.z + a0.z, x0.w + a0.w);
    *(float4*)&g_xga[((size_t)(j0 + 1) * HH + t) * 4] = make_float4(x1.x + a1.x, x1.y + a1.y, x1.z + a1.z, x1.w + a1.w);
    *(float4*)&g_xga[((size_t)(j0 + 2) * HH + t) * 4] = make_float4(x2.x + a2.x, x2.y + a2.y, x2.z + a2.z, x2.w + a2.w);
    *(float4*)&g_xga[((size_t)(j0 + 3) * HH + t) * 4] = make_float4(x3.x + a3.x, x3.y + a3.y, x3.z + a3.z, x3.w + a3.w);
  } else {
    *(float4*)&g_hws[((size_t)(j0 + 0) * HH + t) * 4] = a0;
    *(float4*)&g_hws[((size_t)(j0 + 1) * HH + t) * 4] = a1;
    *(float4*)&g_hws[((size_t)(j0 + 2) * HH + t) * 4] = a2;
    *(float4*)&g_hws[((size_t)(j0 + 3) * HH + t) * 4] = a3;
  }
}

extern "C" void kernel_launch(void* const* d_in, const int* in_sizes, int n_in,
                              void* d_out, int out_size, void* d_ws, size_t ws_size,
                              hipStream_t stream) {
  const float* NE  = (const float*)d_in[0];
  const float* SE  = (const float*)d_in[1];
  const float* Wx  = (const float*)d_in[2];
  const float* Wh  = (const float*)d_in[3];
  const float* b   = (const float*)d_in[4];
  const float* Wxs = (const float*)d_in[5];
  const float* Whs = (const float*)d_in[6];
  const float* bs  = (const float*)d_in[7];
  const float* Wb  = (const float*)d_in[8];
  const float* bb  = (const float*)d_in[9];
  const float* Wk  = (const float*)d_in[10];
  const float* bk  = (const float*)d_in[11];
  // d_in[12] Wq, d_in[13] bq, d_in[15] bl: cancel in row-softmax -> unused
  const float* Wl  = (const float*)d_in[14];
  const float* Wd  = (const float*)d_in[16];
  const float* bd  = (const float*)d_in[17];
  // d_in[18] skip_mask is structurally triu -> computed as (j >= i)
  const int* tix = (const int*)d_in[19];
  const int* fix = (const int*)d_in[20];
  const int* ei  = (const int*)d_in[21];
  float* out = (float*)d_out;

  k_pre<<<180, 512, 0, stream>>>(NE, Wx, b, Wxs, Wk, bs, Wh, Whs);
  k_gemm<<<1920, 256, 0, stream>>>(SE, bk, Wl);
  k_softmax<<<256, 256, 0, stream>>>();
  for (int s = 0; s < 4; ++s) {
    k_step<<<256 + NN * 16, 128, 0, stream>>>(Wb, bb, tix, fix);
    k_finish<<<64, 256, 0, stream>>>(s == 3, Wd, bd, ei, out);
  }
}